// Round 2
// baseline (399.438 us; speedup 1.0000x reference)
//
#include <hip/hip_runtime.h>

#define NDIMC 2
#define NCELLS 1000
#define BATCHSZ 4
#define NSTEPS 251
#define XROW 2007   // 2 + NCELLS*NDIM + 5

__device__ __forceinline__ float fast_tanh(float x) {
    // tanh(x) = 1 - 2/(exp(2x)+1); exp2 form, exact +-1 saturation
    float e = __builtin_amdgcn_exp2f(x * 2.885390081777926774f);
    float r = __builtin_amdgcn_rcpf(e + 1.0f);
    return fmaf(-2.0f, r, 1.0f);
}

// Single-wave workgroup: only need the DS queue drained between write & read.
// No s_barrier, and crucially NO vmcnt drain (dw prefetch stays in flight).
#define LDS_FENCE() asm volatile("s_waitcnt lgkmcnt(0)" ::: "memory")

__device__ __forceinline__ float dot8(const float (&w)[8], const float* lds) {
    float4 v0 = *(const float4*)(lds + 0);
    float4 v1 = *(const float4*)(lds + 4);
    float a0 = w[0]*v0.x, a1 = w[1]*v0.y, a2 = w[2]*v0.z, a3 = w[3]*v0.w;
    a0 = fmaf(w[4], v1.x, a0); a1 = fmaf(w[5], v1.y, a1);
    a2 = fmaf(w[6], v1.z, a2); a3 = fmaf(w[7], v1.w, a3);
    return (a0 + a1) + (a2 + a3);
}

__device__ __forceinline__ float dot16(const float (&w)[16], const float* lds) {
    float4 v0 = *(const float4*)(lds + 0);
    float4 v1 = *(const float4*)(lds + 4);
    float4 v2 = *(const float4*)(lds + 8);
    float4 v3 = *(const float4*)(lds + 12);
    float a0 = w[0]*v0.x, a1 = w[1]*v0.y, a2 = w[2]*v0.z, a3 = w[3]*v0.w;
    a0 = fmaf(w[4],  v1.x, a0); a1 = fmaf(w[5],  v1.y, a1);
    a2 = fmaf(w[6],  v1.z, a2); a3 = fmaf(w[7],  v1.w, a3);
    a0 = fmaf(w[8],  v2.x, a0); a1 = fmaf(w[9],  v2.y, a1);
    a2 = fmaf(w[10], v2.z, a2); a3 = fmaf(w[11], v2.w, a3);
    a0 = fmaf(w[12], v3.x, a0); a1 = fmaf(w[13], v3.y, a1);
    a2 = fmaf(w[14], v3.z, a2); a3 = fmaf(w[15], v3.w, a3);
    return (a0 + a1) + (a2 + a3);
}

__global__ __launch_bounds__(64, 4)
void phinn_sde_kernel(const float* __restrict__ x,   const float* __restrict__ dw,
                      const float* __restrict__ pw1, const float* __restrict__ pb1,
                      const float* __restrict__ pw2, const float* __restrict__ pb2,
                      const float* __restrict__ pw3, const float* __restrict__ pb3,
                      const float* __restrict__ pw4, const float* __restrict__ pb4,
                      const float* __restrict__ pw5, const float* __restrict__ pb5,
                      const float* __restrict__ tw,  const float* __restrict__ tb,
                      float* __restrict__ out)
{
    // per-half stage buffers; stages: 0:h1 1:h2 2:h3 3:g4 4:g3 5:g2
    __shared__ float sh[2][6][32];

    const int tid = threadIdx.x;
    const int n   = tid & 31;          // neuron id (32-wide layers)
    const int h   = tid >> 5;          // k-range half
    const int s16 = n & 15;            // neuron id (16-wide layers)
    const int q   = (n >> 4) + 2 * h;  // k-range quarter (16-out layers)
    const int b    = blockIdx.x / NCELLS;
    const int cell = blockIdx.x % NCELLS;

    // ---- register-resident weight fragments (loaded once, used 251x) ----
    const float r1a = pw1[s16 * 2 + 0];
    const float r1b = pw1[s16 * 2 + 1];
    const float rb1 = pb1[s16];

    float w2r[8];                       // pw2 row n, k-half h
    #pragma unroll
    for (int j = 0; j < 8; ++j) w2r[j] = pw2[n * 16 + h * 8 + j];
    const float rb2 = pb2[n];

    float w3r[16];                      // pw3 row n, k-half h
    #pragma unroll
    for (int j = 0; j < 16; ++j) w3r[j] = pw3[n * 32 + h * 16 + j];
    const float rb3 = pb3[n];

    float w4r[8];                       // pw4 row s16, k-quarter q
    #pragma unroll
    for (int j = 0; j < 8; ++j) w4r[j] = pw4[s16 * 32 + q * 8 + j];
    const float rb4 = pb4[s16];

    const float rw5 = pw5[s16];

    float w4c[8];                       // pw4 column n, j-half h   (for g3)
    #pragma unroll
    for (int j = 0; j < 8; ++j) w4c[j] = pw4[(h * 8 + j) * 32 + n];

    float w3c[16];                      // pw3 column n, j-half h   (for g2)
    #pragma unroll
    for (int j = 0; j < 16; ++j) w3c[j] = pw3[(h * 16 + j) * 32 + n];

    float w2c[8];                       // pw2 column s16, j-quarter q (for g1)
    #pragma unroll
    for (int j = 0; j < 8; ++j) w2c[j] = pw2[(q * 8 + j) * 16 + s16];

    // ---- per-batch scalars & both tilt candidates ----
    const float* xb = x + (size_t)b * XROW;
    const float t0v    = xb[0];
    const float tcritv = xb[2 + NCELLS * NDIMC];
    const float p0x = xb[2003], p0y = xb[2004];
    const float p1x = xb[2005], p1y = xb[2006];
    const float tA0 = fmaf(p0x, tw[0], fmaf(p0y, tw[1], tb[0]));
    const float tA1 = fmaf(p0x, tw[2], fmaf(p0y, tw[3], tb[1]));
    const float tB0 = fmaf(p1x, tw[0], fmaf(p1y, tw[1], tb[0]));
    const float tB1 = fmaf(p1x, tw[2], fmaf(p1y, tw[3], tb[1]));

    float y0 = xb[2 + cell * 2 + 0];
    float y1 = xb[2 + cell * 2 + 1];

    // opaque zero: forces the dw load onto the VMEM (vmcnt) path so our
    // lgkmcnt fences never drain it -> full-step prefetch distance
    int zz;
    asm("v_mov_b32 %0, 0" : "=v"(zz));
    const float* dwp = dw + ((size_t)b * NSTEPS * NCELLS + cell) * NDIMC;

    // LDS addressing: write slot n of own half; reads pick k-ranges
    float*       wr  = &sh[h][0][n];        // wr[stage*32]
    const float* r8  = &sh[h][0][h * 8];    // half-split dot8
    const float* r16 = &sh[h][0][h * 16];   // half-split dot16
    const float* rq  = &sh[h][0][q * 8];    // quarter-split dot8

    #pragma unroll 1
    for (int i = 0; i < NSTEPS; ++i) {
        const float2 dwv = *(const float2*)(dwp + zz);   // VMEM prefetch
        dwp += NCELLS * NDIMC;
        const float t = t0v + 0.001f * (float)i;

        // ---------- forward ----------
        const float h1 = fast_tanh(fmaf(r1a, y0, fmaf(r1b, y1, rb1)));
        wr[0] = h1;                                   // slots 16..31 = dup, unread
        LDS_FENCE();

        float a = dot8(w2r, r8 + 0);
        a += __shfl_xor(a, 32, 64);
        const float h2 = fast_tanh(a + rb2);
        wr[32] = h2;
        LDS_FENCE();

        a = dot16(w3r, r16 + 32);
        a += __shfl_xor(a, 32, 64);
        const float h3 = fast_tanh(a + rb3);
        wr[64] = h3;
        LDS_FENCE();

        a = dot8(w4r, rq + 64);
        a += __shfl_xor(a, 16, 64);
        a += __shfl_xor(a, 32, 64);
        const float h4 = fast_tanh(a + rb4);

        // ---------- backward ----------
        const float g4 = rw5 * fmaf(-h4, h4, 1.0f);
        wr[96] = g4;
        LDS_FENCE();

        a = dot8(w4c, r8 + 96);
        a += __shfl_xor(a, 32, 64);
        const float g3 = a * fmaf(-h3, h3, 1.0f);
        wr[128] = g3;
        LDS_FENCE();

        a = dot16(w3c, r16 + 128);
        a += __shfl_xor(a, 32, 64);
        const float g2 = a * fmaf(-h2, h2, 1.0f);
        wr[160] = g2;
        LDS_FENCE();

        a = dot8(w2c, rq + 160);
        a += __shfl_xor(a, 16, 64);
        a += __shfl_xor(a, 32, 64);
        const float g1 = a * fmaf(-h1, h1, 1.0f);

        // gy[d] = sum_rows pw1[row][d] * g1[row]; rows live in lanes n<16 of
        // each half (halves identical), butterfly within each 32-group
        float v0 = (n < 16) ? r1a * g1 : 0.0f;
        float v1 = (n < 16) ? r1b * g1 : 0.0f;
        #pragma unroll
        for (int m = 1; m < 32; m <<= 1) {
            v0 += __shfl_xor(v0, m, 64);
            v1 += __shfl_xor(v1, m, 64);
        }

        // ---------- update (identical in all 64 lanes) ----------
        const bool  cnd   = t < tcritv;
        const float tilt0 = cnd ? tA0 : tB0;
        const float tilt1 = cnd ? tA1 : tB1;
        y0 = fmaf(-0.001f, v0 + tilt0, fmaf(0.001f, dwv.x, y0));
        y1 = fmaf(-0.001f, v1 + tilt1, fmaf(0.001f, dwv.y, y1));
    }

    if (tid == 0) {
        *(float2*)(out + ((size_t)b * NCELLS + cell) * NDIMC) = make_float2(y0, y1);
    }
}

extern "C" void kernel_launch(void* const* d_in, const int* in_sizes, int n_in,
                              void* d_out, int out_size, void* d_ws, size_t ws_size,
                              hipStream_t stream) {
    const float* x   = (const float*)d_in[0];
    const float* dw  = (const float*)d_in[1];
    const float* pw1 = (const float*)d_in[2];
    const float* pb1 = (const float*)d_in[3];
    const float* pw2 = (const float*)d_in[4];
    const float* pb2 = (const float*)d_in[5];
    const float* pw3 = (const float*)d_in[6];
    const float* pb3 = (const float*)d_in[7];
    const float* pw4 = (const float*)d_in[8];
    const float* pb4 = (const float*)d_in[9];
    const float* pw5 = (const float*)d_in[10];
    const float* pb5 = (const float*)d_in[11];
    const float* tw  = (const float*)d_in[12];
    const float* tb  = (const float*)d_in[13];
    float* out = (float*)d_out;

    dim3 grid(BATCHSZ * NCELLS);   // 4000 single-wave blocks, 1 cell each
    dim3 block(64);
    phinn_sde_kernel<<<grid, block, 0, stream>>>(x, dw, pw1, pb1, pw2, pb2,
                                                 pw3, pb3, pw4, pb4, pw5, pb5,
                                                 tw, tb, out);
}

// Round 3
// 307.495 us; speedup vs baseline: 1.2990x; 1.2990x over previous
//
#include <hip/hip_runtime.h>

#define NDIMC 2
#define NCELLS 1000
#define BATCHSZ 4
#define NSTEPS 251
#define XROW 2007   // 2 + NCELLS*NDIM + 5

__device__ __forceinline__ float fast_tanh(float x) {
    // tanh(x) = 1 - 2/(exp(2x)+1); exp2 form, exact +-1 saturation
    float e = __builtin_amdgcn_exp2f(x * 2.885390081777926774f);
    float r = __builtin_amdgcn_rcpf(e + 1.0f);
    return fmaf(-2.0f, r, 1.0f);
}

// Single-wave workgroup: only the DS queue needs draining between the LDS
// write and the dependent reads. No s_barrier, no vmcnt drain (keeps the dw
// prefetch in flight across the whole step).
#define LDS_FENCE() asm volatile("s_waitcnt lgkmcnt(0)" ::: "memory")

// Packed fp32 FMA: 2 independent FMAs per instruction (VOP3P).
__device__ __forceinline__ void pkfma(float2& acc, float2 w, float2 v) {
    asm("v_pk_fma_f32 %0, %1, %2, %0" : "+v"(acc) : "v"(w), "v"(v));
}

__device__ __forceinline__ float pdot16(const float2 (&w)[8], const float* lds,
                                        float bias) {
    const float4 v0 = *(const float4*)(lds + 0);
    const float4 v1 = *(const float4*)(lds + 4);
    const float4 v2 = *(const float4*)(lds + 8);
    const float4 v3 = *(const float4*)(lds + 12);
    float2 a0 = make_float2(bias, 0.f), a1 = make_float2(0.f, 0.f);
    pkfma(a0, w[0], make_float2(v0.x, v0.y)); pkfma(a1, w[1], make_float2(v0.z, v0.w));
    pkfma(a0, w[2], make_float2(v1.x, v1.y)); pkfma(a1, w[3], make_float2(v1.z, v1.w));
    pkfma(a0, w[4], make_float2(v2.x, v2.y)); pkfma(a1, w[5], make_float2(v2.z, v2.w));
    pkfma(a0, w[6], make_float2(v3.x, v3.y)); pkfma(a1, w[7], make_float2(v3.z, v3.w));
    return (a0.x + a0.y) + (a1.x + a1.y);
}

__device__ __forceinline__ float pdot32(const float2 (&w)[16], const float* lds,
                                        float bias) {
    float2 a0 = make_float2(bias, 0.f), a1 = make_float2(0.f, 0.f);
    #pragma unroll
    for (int c = 0; c < 4; ++c) {
        const float4 u0 = *(const float4*)(lds + c * 8);
        const float4 u1 = *(const float4*)(lds + c * 8 + 4);
        pkfma(a0, w[c*4+0], make_float2(u0.x, u0.y));
        pkfma(a1, w[c*4+1], make_float2(u0.z, u0.w));
        pkfma(a0, w[c*4+2], make_float2(u1.x, u1.y));
        pkfma(a1, w[c*4+3], make_float2(u1.z, u1.w));
    }
    return (a0.x + a0.y) + (a1.x + a1.y);
}

__global__ __launch_bounds__(64, 2)
void phinn_sde_kernel(const float* __restrict__ x,   const float* __restrict__ dw,
                      const float* __restrict__ pw1, const float* __restrict__ pb1,
                      const float* __restrict__ pw2, const float* __restrict__ pb2,
                      const float* __restrict__ pw3, const float* __restrict__ pb3,
                      const float* __restrict__ pw4, const float* __restrict__ pb4,
                      const float* __restrict__ pw5, const float* __restrict__ pb5,
                      const float* __restrict__ tw,  const float* __restrict__ tb,
                      float* __restrict__ out)
{
    // stages: 0:h1(16) 1:h2(32) 2:h3(32) 3:g4pre(16) 4:g3pre(32) 5:g2pre(32)
    __shared__ float sh[2][6][32];

    const int tid  = threadIdx.x;
    const int n    = tid & 31;          // neuron id within 32-group
    const int grp  = tid >> 5;          // which of the wave's two cells
    const int s16  = n & 15;
    const int b    = blockIdx.x / (NCELLS / 2);
    const int pair = blockIdx.x % (NCELLS / 2);
    const int cell = pair * 2 + grp;

    // ---- per-lane register-resident weights (loaded once, used 251x) ----
    const float r1a = pw1[s16 * 2 + 0];
    const float r1b = pw1[s16 * 2 + 1];
    const float rb1 = pb1[s16];

    float2 w2p[8];                       // pw2 row n (16 in), packed pairs
    #pragma unroll
    for (int j = 0; j < 8; ++j) w2p[j] = ((const float2*)pw2)[n * 8 + j];
    const float rb2 = pb2[n];

    float2 w3p[16];                      // pw3 row n
    #pragma unroll
    for (int j = 0; j < 16; ++j) w3p[j] = ((const float2*)pw3)[n * 16 + j];
    const float rb3 = pb3[n];

    float2 w4p[16];                      // pw4 row s16
    #pragma unroll
    for (int j = 0; j < 16; ++j) w4p[j] = ((const float2*)pw4)[s16 * 16 + j];
    const float rb4 = pb4[s16];

    const float rw5 = pw5[s16];

    float2 w4cp[8];                      // pw4 column n (for g3), packed over j
    #pragma unroll
    for (int j = 0; j < 8; ++j)
        w4cp[j] = make_float2(pw4[(2*j) * 32 + n], pw4[(2*j+1) * 32 + n]);

    float2 w3cp[16];                     // pw3 column n (for g2)
    #pragma unroll
    for (int j = 0; j < 16; ++j)
        w3cp[j] = make_float2(pw3[(2*j) * 32 + n], pw3[(2*j+1) * 32 + n]);

    float2 w2cp[16];                     // pw2 column s16 (for g1)
    #pragma unroll
    for (int j = 0; j < 16; ++j)
        w2cp[j] = make_float2(pw2[(2*j) * 16 + s16], pw2[(2*j+1) * 16 + s16]);

    // ---- per-batch scalars & both tilt candidates ----
    const float* xb = x + (size_t)b * XROW;
    const float t0v    = xb[0];
    const float tcritv = xb[2 + NCELLS * NDIMC];       // index 2002
    const float p0x = xb[2003], p0y = xb[2004];
    const float p1x = xb[2005], p1y = xb[2006];
    const float tA0 = fmaf(p0x, tw[0], fmaf(p0y, tw[1], tb[0]));
    const float tA1 = fmaf(p0x, tw[2], fmaf(p0y, tw[3], tb[1]));
    const float tB0 = fmaf(p1x, tw[0], fmaf(p1y, tw[1], tb[0]));
    const float tB1 = fmaf(p1x, tw[2], fmaf(p1y, tw[3], tb[1]));

    float y0 = xb[2 + cell * 2 + 0];
    float y1 = xb[2 + cell * 2 + 1];

    const float* dwp = dw + ((size_t)b * NSTEPS * NCELLS + cell) * NDIMC;

    const float* l0 = &sh[grp][0][0];
    const float* l1 = &sh[grp][1][0];
    const float* l2 = &sh[grp][2][0];
    const float* l3 = &sh[grp][3][0];
    const float* l4 = &sh[grp][4][0];
    const float* l5 = &sh[grp][5][0];

    #pragma unroll 1
    for (int i = 0; i < NSTEPS; ++i) {
        // prefetch this step's noise early; consumed at the very end
        const float2 dwv = *(const float2*)dwp;
        dwp += NCELLS * NDIMC;
        const float t = t0v + 0.001f * (float)i;

        // ---------- forward ----------
        const float h1 = fast_tanh(fmaf(r1a, y0, fmaf(r1b, y1, rb1)));
        if (n < 16) sh[grp][0][n] = h1;
        LDS_FENCE();

        const float h2 = fast_tanh(pdot16(w2p, l0, rb2));
        sh[grp][1][n] = h2;
        LDS_FENCE();

        const float h3 = fast_tanh(pdot32(w3p, l1, rb3));
        sh[grp][2][n] = h3;
        LDS_FENCE();

        const float h4 = fast_tanh(pdot32(w4p, l2, rb4));

        // ---------- backward (grad of sum(phi) wrt y) ----------
        const float g4p = rw5 * fmaf(-h4, h4, 1.0f);
        if (n < 16) sh[grp][3][n] = g4p;
        LDS_FENCE();

        const float g3p = pdot16(w4cp, l3, 0.f) * fmaf(-h3, h3, 1.0f);
        sh[grp][4][n] = g3p;
        LDS_FENCE();

        const float g2p = pdot32(w3cp, l4, 0.f) * fmaf(-h2, h2, 1.0f);
        sh[grp][5][n] = g2p;
        LDS_FENCE();

        const float g1p = pdot32(w2cp, l5, 0.f) * fmaf(-h1, h1, 1.0f);

        // gy[d] = sum_{j<16} pw1[j][d] * g1p[j].  Half-split: lanes n<16
        // accumulate the r1a component, lanes n>=16 the r1b component
        // (g1p is s16-indexed, duplicated across halves of the 32-group).
        float z = ((n & 16) ? r1b : r1a) * g1p;
        #pragma unroll
        for (int m = 1; m < 16; m <<= 1) z += __shfl_xor(z, m, 64);
        const float o  = __shfl_xor(z, 16, 64);
        const float v0 = (n & 16) ? o : z;
        const float v1 = (n & 16) ? z : o;

        // ---------- update (identical in all lanes of the group) ----------
        const bool  cnd   = t < tcritv;
        const float tilt0 = cnd ? tA0 : tB0;
        const float tilt1 = cnd ? tA1 : tB1;
        y0 = fmaf(-0.001f, v0 + tilt0, fmaf(0.001f, dwv.x, y0));
        y1 = fmaf(-0.001f, v1 + tilt1, fmaf(0.001f, dwv.y, y1));
    }

    if (n == 0) {
        *(float2*)(out + ((size_t)b * NCELLS + cell) * NDIMC) = make_float2(y0, y1);
    }
}

extern "C" void kernel_launch(void* const* d_in, const int* in_sizes, int n_in,
                              void* d_out, int out_size, void* d_ws, size_t ws_size,
                              hipStream_t stream) {
    const float* x   = (const float*)d_in[0];
    const float* dw  = (const float*)d_in[1];
    const float* pw1 = (const float*)d_in[2];
    const float* pb1 = (const float*)d_in[3];
    const float* pw2 = (const float*)d_in[4];
    const float* pb2 = (const float*)d_in[5];
    const float* pw3 = (const float*)d_in[6];
    const float* pb3 = (const float*)d_in[7];
    const float* pw4 = (const float*)d_in[8];
    const float* pb4 = (const float*)d_in[9];
    const float* pw5 = (const float*)d_in[10];
    const float* pb5 = (const float*)d_in[11];
    const float* tw  = (const float*)d_in[12];
    const float* tb  = (const float*)d_in[13];
    float* out = (float*)d_out;

    dim3 grid(BATCHSZ * NCELLS / 2);   // 2000 single-wave blocks (2 cells each)
    dim3 block(64);
    phinn_sde_kernel<<<grid, block, 0, stream>>>(x, dw, pw1, pb1, pw2, pb2,
                                                 pw3, pb3, pw4, pb4, pw5, pb5,
                                                 tw, tb, out);
}

// Round 4
// 296.230 us; speedup vs baseline: 1.3484x; 1.0380x over previous
//
#include <hip/hip_runtime.h>

#define NDIMC 2
#define NCELLS 1000
#define BATCHSZ 4
#define NSTEPS 251
#define XROW 2007   // 2 + NCELLS*NDIM + 5

__device__ __forceinline__ float fast_tanh(float x) {
    // tanh(x) = 1 - 2/(exp(2x)+1); exp2 form, exact +-1 saturation
    float e = __builtin_amdgcn_exp2f(x * 2.885390081777926774f);
    float r = __builtin_amdgcn_rcpf(e + 1.0f);
    return fmaf(-2.0f, r, 1.0f);
}

// Single-wave workgroup: only the DS queue needs draining between the LDS
// write and the dependent reads. No s_barrier, no vmcnt drain (keeps the dw
// prefetch in flight across the whole step).
#define LDS_FENCE() asm volatile("s_waitcnt lgkmcnt(0)" ::: "memory")

// Packed fp32 ops (VOP3P): 2 independent lanes of fp32 per instruction.
__device__ __forceinline__ void pkfma(float2& a, float2 w, float2 v) {
    asm("v_pk_fma_f32 %0, %1, %2, %0" : "+v"(a) : "v"(w), "v"(v));
}
__device__ __forceinline__ float2 pkadd(float2 a, float2 b) {
    float2 r;
    asm("v_pk_add_f32 %0, %1, %2" : "=v"(r) : "v"(a), "v"(b));
    return r;
}

// VALU cross-lane add via DPP (no DS pipe, ~8cy vs ~120cy ds_swizzle).
template<int CTRL>
__device__ __forceinline__ float dpp_xor_add(float z) {
    int t = __builtin_amdgcn_update_dpp(0, __float_as_int(z), CTRL, 0xf, 0xf, true);
    return z + __int_as_float(t);
}
// Sum over each 16-lane row: xor masks {1,3,7,15} (independent -> full sum
// in every lane). quad_perm(1,0,3,2)=0xB1, quad_perm(3,2,1,0)=0x1B,
// row_half_mirror=0x141 (xor7), row_mirror=0x140 (xor15).
__device__ __forceinline__ float row16_sum(float z) {
    z = dpp_xor_add<0xB1>(z);
    z = dpp_xor_add<0x1B>(z);
    z = dpp_xor_add<0x141>(z);
    z = dpp_xor_add<0x140>(z);
    return z;
}

__device__ __forceinline__ float pdot16(const float2 (&w)[8], const float* lds,
                                        float bias) {
    const float4 v0 = *(const float4*)(lds + 0);
    const float4 v1 = *(const float4*)(lds + 4);
    const float4 v2 = *(const float4*)(lds + 8);
    const float4 v3 = *(const float4*)(lds + 12);
    float2 a0 = make_float2(bias, 0.f), a1 = make_float2(0.f, 0.f);
    float2 a2 = make_float2(0.f, 0.f),  a3 = make_float2(0.f, 0.f);
    pkfma(a0, w[0], make_float2(v0.x, v0.y)); pkfma(a1, w[1], make_float2(v0.z, v0.w));
    pkfma(a2, w[2], make_float2(v1.x, v1.y)); pkfma(a3, w[3], make_float2(v1.z, v1.w));
    pkfma(a0, w[4], make_float2(v2.x, v2.y)); pkfma(a1, w[5], make_float2(v2.z, v2.w));
    pkfma(a2, w[6], make_float2(v3.x, v3.y)); pkfma(a3, w[7], make_float2(v3.z, v3.w));
    float2 s = pkadd(pkadd(a0, a1), pkadd(a2, a3));
    return s.x + s.y;
}

__device__ __forceinline__ float pdot32(const float2 (&w)[16], const float* lds,
                                        float bias) {
    float2 a0 = make_float2(bias, 0.f), a1 = make_float2(0.f, 0.f);
    float2 a2 = make_float2(0.f, 0.f),  a3 = make_float2(0.f, 0.f);
    #pragma unroll
    for (int c = 0; c < 2; ++c) {
        const float4 u0 = *(const float4*)(lds + c * 16 + 0);
        const float4 u1 = *(const float4*)(lds + c * 16 + 4);
        const float4 u2 = *(const float4*)(lds + c * 16 + 8);
        const float4 u3 = *(const float4*)(lds + c * 16 + 12);
        pkfma(a0, w[c*8+0], make_float2(u0.x, u0.y));
        pkfma(a1, w[c*8+1], make_float2(u0.z, u0.w));
        pkfma(a2, w[c*8+2], make_float2(u1.x, u1.y));
        pkfma(a3, w[c*8+3], make_float2(u1.z, u1.w));
        pkfma(a0, w[c*8+4], make_float2(u2.x, u2.y));
        pkfma(a1, w[c*8+5], make_float2(u2.z, u2.w));
        pkfma(a2, w[c*8+6], make_float2(u3.x, u3.y));
        pkfma(a3, w[c*8+7], make_float2(u3.z, u3.w));
    }
    float2 s = pkadd(pkadd(a0, a1), pkadd(a2, a3));
    return s.x + s.y;
}

__global__ __launch_bounds__(64, 2)
void phinn_sde_kernel(const float* __restrict__ x,   const float* __restrict__ dw,
                      const float* __restrict__ pw1, const float* __restrict__ pb1,
                      const float* __restrict__ pw2, const float* __restrict__ pb2,
                      const float* __restrict__ pw3, const float* __restrict__ pb3,
                      const float* __restrict__ pw4, const float* __restrict__ pb4,
                      const float* __restrict__ pw5, const float* __restrict__ pb5,
                      const float* __restrict__ tw,  const float* __restrict__ tb,
                      float* __restrict__ out)
{
    // stages: 0:h1(16) 1:h2(32) 2:h3(32) 3:g4pre(16) 4:g3pre(32) 5:g2pre(32)
    __shared__ float sh[2][6][32];

    const int tid  = threadIdx.x;
    const int n    = tid & 31;          // neuron id within 32-group
    const int grp  = tid >> 5;          // which of the wave's two cells
    const int s16  = n & 15;
    const int b    = blockIdx.x / (NCELLS / 2);
    const int pair = blockIdx.x % (NCELLS / 2);
    const int cell = pair * 2 + grp;

    // ---- per-lane register-resident weights (loaded once, used 251x) ----
    const float r1a = pw1[s16 * 2 + 0];
    const float r1b = pw1[s16 * 2 + 1];
    const float rb1 = pb1[s16];

    float2 w2p[8];                       // pw2 row n (16 in), packed pairs
    #pragma unroll
    for (int j = 0; j < 8; ++j) w2p[j] = ((const float2*)pw2)[n * 8 + j];
    const float rb2 = pb2[n];

    float2 w3p[16];                      // pw3 row n
    #pragma unroll
    for (int j = 0; j < 16; ++j) w3p[j] = ((const float2*)pw3)[n * 16 + j];
    const float rb3 = pb3[n];

    float2 w4p[16];                      // pw4 row s16
    #pragma unroll
    for (int j = 0; j < 16; ++j) w4p[j] = ((const float2*)pw4)[s16 * 16 + j];
    const float rb4 = pb4[s16];

    const float rw5 = pw5[s16];

    float2 w4cp[8];                      // pw4 column n (for g3), packed over j
    #pragma unroll
    for (int j = 0; j < 8; ++j)
        w4cp[j] = make_float2(pw4[(2*j) * 32 + n], pw4[(2*j+1) * 32 + n]);

    float2 w3cp[16];                     // pw3 column n (for g2)
    #pragma unroll
    for (int j = 0; j < 16; ++j)
        w3cp[j] = make_float2(pw3[(2*j) * 32 + n], pw3[(2*j+1) * 32 + n]);

    float2 w2cp[16];                     // pw2 column s16 (for g1)
    #pragma unroll
    for (int j = 0; j < 16; ++j)
        w2cp[j] = make_float2(pw2[(2*j) * 16 + s16], pw2[(2*j+1) * 16 + s16]);

    // ---- per-batch scalars & both tilt candidates ----
    const float* xb = x + (size_t)b * XROW;
    const float t0v    = xb[0];
    const float tcritv = xb[2 + NCELLS * NDIMC];       // index 2002
    const float p0x = xb[2003], p0y = xb[2004];
    const float p1x = xb[2005], p1y = xb[2006];
    const float tA0 = fmaf(p0x, tw[0], fmaf(p0y, tw[1], tb[0]));
    const float tA1 = fmaf(p0x, tw[2], fmaf(p0y, tw[3], tb[1]));
    const float tB0 = fmaf(p1x, tw[0], fmaf(p1y, tw[1], tb[0]));
    const float tB1 = fmaf(p1x, tw[2], fmaf(p1y, tw[3], tb[1]));

    float y0 = xb[2 + cell * 2 + 0];
    float y1 = xb[2 + cell * 2 + 1];

    // dw addressing: uniform SGPR base + per-lane 32-bit element offset
    const float* dwb = dw + (size_t)b * NSTEPS * NCELLS * NDIMC
                          + (size_t)pair * 2 * NDIMC;          // wave-uniform
    int dwoff = grp * NDIMC;                                   // per-lane

    const float* l0 = &sh[grp][0][0];
    const float* l1 = &sh[grp][1][0];
    const float* l2 = &sh[grp][2][0];
    const float* l3 = &sh[grp][3][0];
    const float* l4 = &sh[grp][4][0];
    const float* l5 = &sh[grp][5][0];

    #pragma unroll 1
    for (int i = 0; i < NSTEPS; ++i) {
        // prefetch this step's noise early; consumed at the very end
        const float2 dwv = *(const float2*)(dwb + dwoff);
        dwoff += NCELLS * NDIMC;
        const float t = t0v + 0.001f * (float)i;

        // ---------- forward ----------
        const float h1 = fast_tanh(fmaf(r1a, y0, fmaf(r1b, y1, rb1)));
        sh[grp][0][n] = h1;          // slots 16..31 = dup, never read
        LDS_FENCE();

        const float h2 = fast_tanh(pdot16(w2p, l0, rb2));
        sh[grp][1][n] = h2;
        LDS_FENCE();

        const float h3 = fast_tanh(pdot32(w3p, l1, rb3));
        sh[grp][2][n] = h3;
        LDS_FENCE();

        const float h4 = fast_tanh(pdot32(w4p, l2, rb4));

        // ---------- backward (grad of sum(phi) wrt y) ----------
        const float g4p = rw5 * fmaf(-h4, h4, 1.0f);
        sh[grp][3][n] = g4p;         // slots 16..31 = dup, never read
        LDS_FENCE();

        const float g3p = pdot16(w4cp, l3, 0.f) * fmaf(-h3, h3, 1.0f);
        sh[grp][4][n] = g3p;
        LDS_FENCE();

        const float g2p = pdot32(w3cp, l4, 0.f) * fmaf(-h2, h2, 1.0f);
        sh[grp][5][n] = g2p;
        LDS_FENCE();

        const float g1p = pdot32(w2cp, l5, 0.f) * fmaf(-h1, h1, 1.0f);

        // gy[d] = sum_{j<16} pw1[j][d] * g1p[j]. g1p is duplicated across
        // the 16-halves of each 32-group, so a 16-lane DPP butterfly gives
        // the full sum in every lane -- no DS-pipe ops, no exchange.
        const float v0 = row16_sum(r1a * g1p);
        const float v1 = row16_sum(r1b * g1p);

        // ---------- update (identical in all lanes of the group) ----------
        const bool  cnd   = t < tcritv;
        const float tilt0 = cnd ? tA0 : tB0;
        const float tilt1 = cnd ? tA1 : tB1;
        y0 = fmaf(-0.001f, v0 + tilt0, fmaf(0.001f, dwv.x, y0));
        y1 = fmaf(-0.001f, v1 + tilt1, fmaf(0.001f, dwv.y, y1));
    }

    if (n == 0) {
        *(float2*)(out + ((size_t)b * NCELLS + cell) * NDIMC) = make_float2(y0, y1);
    }
}

extern "C" void kernel_launch(void* const* d_in, const int* in_sizes, int n_in,
                              void* d_out, int out_size, void* d_ws, size_t ws_size,
                              hipStream_t stream) {
    const float* x   = (const float*)d_in[0];
    const float* dw  = (const float*)d_in[1];
    const float* pw1 = (const float*)d_in[2];
    const float* pb1 = (const float*)d_in[3];
    const float* pw2 = (const float*)d_in[4];
    const float* pb2 = (const float*)d_in[5];
    const float* pw3 = (const float*)d_in[6];
    const float* pb3 = (const float*)d_in[7];
    const float* pw4 = (const float*)d_in[8];
    const float* pb4 = (const float*)d_in[9];
    const float* pw5 = (const float*)d_in[10];
    const float* pb5 = (const float*)d_in[11];
    const float* tw  = (const float*)d_in[12];
    const float* tb  = (const float*)d_in[13];
    float* out = (float*)d_out;

    dim3 grid(BATCHSZ * NCELLS / 2);   // 2000 single-wave blocks (2 cells each)
    dim3 block(64);
    phinn_sde_kernel<<<grid, block, 0, stream>>>(x, dw, pw1, pb1, pw2, pb2,
                                                 pw3, pb3, pw4, pb4, pw5, pb5,
                                                 tw, tb, out);
}